// Round 18
// baseline (507.804 us; speedup 1.0000x reference)
//
#include <hip/hip_runtime.h>

typedef unsigned short u16;
typedef unsigned int u32;
typedef __bf16 bf16_t;
typedef bf16_t bf16x8 __attribute__((ext_vector_type(8)));
typedef float f32x4 __attribute__((ext_vector_type(4)));

#define B_ 2
#define S_ 2048
#define DIM_ 4096
#define NH_ 32
#define NKV_ 8
#define HD_ 128

__device__ __forceinline__ u16 f2b(float f) {
  union { float f; unsigned u; } x; x.f = f;
  unsigned r = x.u + 0x7fffu + ((x.u >> 16) & 1u);
  return (u16)(r >> 16);
}
__device__ __forceinline__ float b2f(u16 u) {
  union { unsigned u; float f; } x; x.u = ((unsigned)u) << 16;
  return x.f;
}
__device__ __forceinline__ u32 cvtpk(float lo, float hi) {
  u32 r;
  asm volatile("v_cvt_pk_bf16_f32 %0, %1, %2" : "=v"(r) : "v"(lo), "v"(hi));
  return r;
}
// cross-lane reduce over lanes {l, l^16, l^32, l^48} — proven shfl_xor path
__device__ __forceinline__ float redmax4(float x) {
  x = fmaxf(x, __shfl_xor(x, 16));
  x = fmaxf(x, __shfl_xor(x, 32));
  return x;
}
__device__ __forceinline__ float redsum4(float x) {
  x += __shfl_xor(x, 16);
  x += __shfl_xor(x, 32);
  return x;
}

#define GLDS(gsrc, ldst) \
  __builtin_amdgcn_global_load_lds((const __attribute__((address_space(1))) void*)(gsrc), \
                                   (__attribute__((address_space(3))) void*)(ldst), 16, 0, 0)
#define BAR()    __builtin_amdgcn_s_barrier()
#define SCHED0() __builtin_amdgcn_sched_barrier(0)

// ---------------- f32 -> bf16 conversion ----------------
__global__ void cvt_kernel(const float* __restrict__ in, u16* __restrict__ out, int n4) {
  int i = blockIdx.x * blockDim.x + threadIdx.x;
  int stride = gridDim.x * blockDim.x;
  for (; i < n4; i += stride) {
    float4 v = ((const float4*)in)[i];
    ushort4 o;
    o.x = f2b(v.x); o.y = f2b(v.y); o.z = f2b(v.z); o.w = f2b(v.w);
    ((ushort4*)out)[i] = o;
  }
}

// ---------------- RoPE (in-place on bf16) — K only ----------------
__global__ void rope_kernel(u16* __restrict__ t, const float* __restrict__ fc,
                            const float* __restrict__ fs, int nheads) {
  int idx = blockIdx.x * blockDim.x + threadIdx.x;
  int ppr = nheads * 64;
  int row = idx / ppr;
  int pr = idx - row * ppr;
  int h = pr >> 6, j = pr & 63;
  int s = row & (S_ - 1);
  float c = fc[s * 64 + j], sn = fs[s * 64 + j];
  u16* p = t + (size_t)row * (size_t)(nheads * HD_) + h * HD_ + j * 2;
  float tr = b2f(p[0]), ti = b2f(p[1]);
  p[0] = f2b(tr * c - ti * sn);
  p[1] = f2b(tr * sn + ti * c);
}

// ---------------- 8-phase GEMM: C = A[M,K] * B[N,K]^T ----------------
// Tile = (SM ? 128 : 256) x 256, BK=64, 8 waves (2M x 4N), dbuf LDS, counted vmcnt.
// Barrier-reduced schedule (10 barriers/iter): per phase
//   [frag ds_reads; BAR; lgkmcnt(0); MFMA burst; stage (post-MFMA)]
// with the post-MFMA barrier kept ONLY at ph3/ph7 (after vmcnt(4)).
// MODE 0: bf16 row-major ld N; MODE 1: f32 row-major ld N;
// MODE 3: dual (col<1024 -> Cout bf16 ld 1024; col>=1024 -> Cout2 bf16 col-major [col-1024][M])
template<int MODE, bool SM>
__global__ __launch_bounds__(512, 2) void gemm256(const u16* __restrict__ A,
                                                  const u16* __restrict__ B,
                                                  void* __restrict__ Cout,
                                                  void* __restrict__ Cout2,
                                                  int M, int N, int K) {
  constexpr int BM = SM ? 128 : 256;
  constexpr int AH = SM ? 4096 : 8192;   // u16 per A-half
  constexpr int II = SM ? 1 : 2;         // m-frags per quadrant
  constexpr int NACC = SM ? 4 : 8;
  __shared__ u16 As[2][2][AH];
  __shared__ u16 Bs[2][2][8192];
  const int nbn = N >> 8;
  const int nwg = gridDim.x;
  int wg = blockIdx.x;
  wg = (wg & 7) * (nwg >> 3) + (wg >> 3);   // XCD swizzle (nwg % 8 == 0)
  const int bm = wg / nbn;
  const int bn = wg - bm * nbn;
  const int tid = threadIdx.x;
  const int lane = tid & 63;
  const int wv = tid >> 6;
  const int wm = wv >> 2, wn = wv & 3;
  const int qloc = lane & 15, grp = lane >> 4;
  const int NT = K >> 6;

  f32x4 acc[NACC][4];
#pragma unroll
  for (int i = 0; i < NACC; i++)
#pragma unroll
    for (int j = 0; j < 4; j++)
#pragma unroll
      for (int r = 0; r < 4; r++) acc[i][j][r] = 0.0f;

  const int srowl = lane >> 3;
  const int scsw = 8 * ((lane & 7) ^ srowl);   // pre-swizzled source col (elems)
  const size_t rowA = SM ? ((size_t)(bm * 128 + wv * 8 + srowl) * K + scsw)
                         : ((size_t)(bm * 256 + wv * 16 + srowl) * K + scsw);
  const size_t rowB = (size_t)(bn * 256 + wv * 16 + srowl) * K + scsw;

#define STAGE_A(buf, h, tt) { \
    if (SM) { \
      GLDS(A + rowA + (size_t)((h) * 64) * K + (size_t)(tt) * 64, &As[buf][h][wv * 512]); \
    } else { \
      GLDS(A + rowA + (size_t)((h) * 128) * K + (size_t)(tt) * 64, &As[buf][h][wv * 1024]); \
      GLDS(A + rowA + (size_t)((h) * 128 + 8) * K + (size_t)(tt) * 64, &As[buf][h][wv * 1024 + 512]); } }
#define STAGE_B(buf, h, tt) { \
    GLDS(B + rowB + (size_t)((h) * 128) * K + (size_t)(tt) * 64, &Bs[buf][h][wv * 1024]); \
    GLDS(B + rowB + (size_t)((h) * 128 + 8) * K + (size_t)(tt) * 64, &Bs[buf][h][wv * 1024 + 512]); }

  // ---- prologue: tile0 (A+B) into buf0, tile1 B into buf1 ----
  STAGE_A(0, 0, 0); STAGE_A(0, 1, 0);
  STAGE_B(0, 0, 0); STAGE_B(0, 1, 0);
  STAGE_B(1, 0, 1); STAGE_B(1, 1, 1);
  asm volatile("s_waitcnt vmcnt(4)" ::: "memory");   // tile0 fully landed
  BAR();

  for (int t = 0; t < NT; t += 2) {
#pragma unroll
    for (int half = 0; half < 2; half++) {
      bf16x8 bfr[4][2];
#pragma unroll
      for (int qd = 0; qd < 4; qd++) {
        if (qd == 0) {
#pragma unroll
          for (int j = 0; j < 4; j++)
#pragma unroll
            for (int ks = 0; ks < 2; ks++) {
              int rb = (wn & 1) * 64 + j * 16 + qloc;
              bfr[j][ks] = *(const bf16x8*)((const char*)&Bs[half][wn >> 1][0]
                           + rb * 128 + ((ks * 64 + grp * 16) ^ ((rb & 7) << 4)));
            }
        }
        bf16x8 af[II][2];
#pragma unroll
        for (int ii = 0; ii < II; ii++)
#pragma unroll
          for (int ks = 0; ks < 2; ks++) {
            int rh = SM ? (qd * 16 + qloc) : (qd * 32 + ii * 16 + qloc);
            af[ii][ks] = *(const bf16x8*)((const char*)&As[half][wm][0]
                         + rh * 128 + ((ks * 64 + grp * 16) ^ ((rh & 7) << 4)));
          }
        BAR();
        asm volatile("s_waitcnt lgkmcnt(0)" ::: "memory");
        SCHED0();
        __builtin_amdgcn_s_setprio(1);
#pragma unroll
        for (int ii = 0; ii < II; ii++)
#pragma unroll
          for (int ks = 0; ks < 2; ks++)
#pragma unroll
            for (int j = 0; j < 4; j++)
              acc[qd * II + ii][j] = __builtin_amdgcn_mfma_f32_16x16x32_bf16(
                  af[ii][ks], bfr[j][ks], acc[qd * II + ii][j], 0, 0, 0);
        __builtin_amdgcn_s_setprio(0);
        SCHED0();
        // ---- stage (post-MFMA; overlaps following phases' reads) ----
        const int ph = half * 4 + qd;
        if (ph == 0)      { STAGE_A(1, 0, t + 1); STAGE_A(1, 1, t + 1); }
        else if (ph == 1) { if (t + 2 < NT) { STAGE_B(0, 0, t + 2); STAGE_B(0, 1, t + 2); } }
        else if (ph == 4) { if (t + 2 < NT) { STAGE_A(0, 0, t + 2); STAGE_A(0, 1, t + 2); } }
        else if (ph == 5) { if (t + 3 < NT) { STAGE_B(1, 0, t + 3); STAGE_B(1, 1, t + 3); } }
        if (qd == 3) {
          if ((half == 0 ? t + 2 : t + 3) < NT)
            asm volatile("s_waitcnt vmcnt(4)" ::: "memory");
          else
            asm volatile("s_waitcnt vmcnt(0)" ::: "memory");
          BAR();
        }
      }
    }
  }
#undef STAGE_A
#undef STAGE_B

  // ---- epilogue ----
  const int r0g = bm * BM + wm * (BM / 2) + grp * 4;
  const int c0g = bn * 256 + wn * 64 + qloc;
#pragma unroll
  for (int i = 0; i < NACC; i++)
#pragma unroll
    for (int j = 0; j < 4; j++)
#pragma unroll
      for (int r = 0; r < 4; r++) {
        int row = r0g + i * 16 + r;
        int col = c0g + j * 16;
        float v = acc[i][j][r];
        if (MODE == 1)      ((float*)Cout)[(size_t)row * N + col] = v;
        else if (MODE == 0) ((u16*)Cout)[(size_t)row * N + col]  = f2b(v);
        else {
          if (col < 1024) ((u16*)Cout)[(size_t)row * 1024 + col] = f2b(v);
          else            ((u16*)Cout2)[(size_t)(col - 1024) * M + row] = f2b(v);
        }
      }
}

// ---------------- Flash attention (causal, GQA 4:1) ----------------
// r12-measured best config: block = 128 q rows of one (b,h); 8 waves x 16 q;
// KV tile = 32, dbuf; grid 1024 (4 blocks/CU, 32 KB LDS).
// __launch_bounds__(512, 4) pins the allocator to a 128-VGPR/wave budget:
// r17 showed module-level codegen perturbation (rule #19) shrank this kernel
// to 44 arch VGPRs + AGPR shuffling (+33 us). Natural demand ~80 fits in 128.
__global__ __launch_bounds__(512, 4) void attn_kernel(const u16* __restrict__ Q,
                                                      const u16* __restrict__ Kt,
                                                      const u16* __restrict__ VT,
                                                      u16* __restrict__ O,
                                                      const float* __restrict__ fc,
                                                      const float* __restrict__ fs) {
  __shared__ u16 Ks[2][32 * 128];
  __shared__ u16 Vs[2][32 * 128];

  const int bid = blockIdx.x;
  const int qb = 15 - (bid >> 6);        // heavy blocks first (128-row q blocks)
  const int h = bid & 31;
  const int b = (bid >> 5) & 1;
  const int g = h >> 2;
  const int tid = threadIdx.x;
  const int lane = tid & 63;
  const int wv = tid >> 6;               // 0..7
  const int qrow0 = qb * 128 + wv * 16;
  const float scl2 = 0.12751744f;        // (1/sqrt(128)) * log2(e)

  const int qloc = lane & 15;
  const int grp = lane >> 4;

  // ---- Q fragment with fused RoPE ----
  bf16x8 qf[4];
  {
    const int qr = qrow0 + qloc;
    const u16* qptr = Q + (size_t)(b * S_ + qr) * (NH_ * HD_) + h * HD_ + grp * 8;
#pragma unroll
    for (int c = 0; c < 4; c++) {
      union { bf16x8 v; u16 u[8]; } raw;
      raw.v = *(const bf16x8*)(qptr + c * 32);
      const int p0 = c * 16 + grp * 4;
      const float4 cv = *(const float4*)&fc[(size_t)qr * 64 + p0];
      const float4 sv = *(const float4*)&fs[(size_t)qr * 64 + p0];
      union { bf16x8 v; u32 w[4]; } out;
      const float cc[4] = {cv.x, cv.y, cv.z, cv.w};
      const float ss[4] = {sv.x, sv.y, sv.z, sv.w};
#pragma unroll
      for (int j = 0; j < 4; j++) {
        float tr = b2f(raw.u[2 * j]), ti = b2f(raw.u[2 * j + 1]);
        out.w[j] = cvtpk(tr * cc[j] - ti * ss[j], tr * ss[j] + ti * cc[j]);
      }
      qf[c] = out.v;
    }
  }

  float m = -1e30f, l = 0.f;
  f32x4 o[8];
#pragma unroll
  for (int c = 0; c < 8; c++)
#pragma unroll
    for (int r = 0; r < 4; r++) o[c][r] = 0.f;

  const int nkv = 4 * qb + 4;            // tiles of 32 keys; always even

  // ---- loop-invariant LDS read byte-offsets ----
  int ka[2][4];
#pragma unroll
  for (int n = 0; n < 2; n++)
#pragma unroll
    for (int c = 0; c < 4; c++) {
      int krow = n * 16 + qloc;
      ka[n][c] = krow * 256 + ((c * 64 + grp * 16) ^ ((krow & 7) << 4));
    }
  int va[8];
#pragma unroll
  for (int c = 0; c < 8; c++) {
    int d = c * 16 + qloc;
    va[c] = d * 64 + ((grp * 16) ^ (((d >> 1) & 3) << 4));
  }

  // ---- staging geometry: 8 waves cover the 32x128 K tile & 128x32 V^T tile ----
  const int kkey = wv * 4 + grp;
  const int cbsK = (qloc * 16) ^ ((kkey & 7) << 4);
  const int vd = wv * 16 + (lane >> 2);
  const int kbsV = ((lane & 3) * 16) ^ (((vd >> 1) & 3) << 4);

  const u16* kp = Kt + (size_t)(b * S_ + kkey) * 1024 + g * HD_ + (cbsK >> 1);
  const u16* vp = VT + (size_t)(g * HD_ + vd) * 4096 + (size_t)b * S_ + (kbsV >> 1);

  // prologue: stage tile 0 into buf 0
  GLDS(kp, &Ks[0][wv * 512]);
  GLDS(vp, &Vs[0][wv * 512]);
  kp += 32 * 1024;   // -> tile 1
  vp += 32;

#define ATTN_ITER(T, CB, NB)                                                   \
  {                                                                            \
    const bool pf = ((T) + 1 < nkv);                                           \
    if (pf) {                                                                  \
      GLDS(kp, &Ks[NB][wv * 512]);                                             \
      GLDS(vp, &Vs[NB][wv * 512]);                                             \
      asm volatile("s_waitcnt vmcnt(2)" ::: "memory");                         \
    } else {                                                                   \
      asm volatile("s_waitcnt vmcnt(0)" ::: "memory");                         \
    }                                                                          \
    BAR();                                                                     \
    SCHED0();                                                                  \
    if ((T) * 32 <= qrow0 + 15) {                                              \
      f32x4 s[2];                                                              \
      __builtin_amdgcn_s_setprio(1);                                           \
      _Pragma("unroll")                                                        \
      for (int n = 0; n < 2; n++) {                                            \
        f32x4 sc;                                                              \
        _Pragma("unroll")                                                      \
        for (int r = 0; r < 4; r++) sc[r] = 0.f;                               \
        _Pragma("unroll")                                                      \
        for (int c = 0; c < 4; c++) {                                          \
          bf16x8 kf = *(const bf16x8*)((const char*)Ks[CB] + ka[n][c]);        \
          sc = __builtin_amdgcn_mfma_f32_16x16x32_bf16(kf, qf[c], sc, 0, 0, 0);\
        }                                                                      \
        s[n] = sc;                                                             \
      }                                                                        \
      __builtin_amdgcn_s_setprio(0);                                           \
      const int q = qrow0 + qloc;                                              \
      if ((T) * 32 + 31 > qrow0) {                                             \
        _Pragma("unroll")                                                      \
        for (int n = 0; n < 2; n++)                                            \
          _Pragma("unroll")                                                    \
          for (int r = 0; r < 4; r++) {                                        \
            int k = (T) * 32 + n * 16 + grp * 4 + r;                           \
            if (k > q) s[n][r] = -1e9f;                                        \
          }                                                                    \
      }                                                                        \
      float pmax = fmaxf(fmaxf(fmaxf(s[0][0], s[0][1]), fmaxf(s[0][2], s[0][3])), \
                         fmaxf(fmaxf(s[1][0], s[1][1]), fmaxf(s[1][2], s[1][3]))); \
      pmax = redmax4(pmax);                                                    \
      if (__any(pmax > m + 64.f)) {                                            \
        float mn = fmaxf(m, pmax);                                             \
        float alpha = exp2f((m - mn) * scl2);                                  \
        m = mn;                                                                \
        l *= alpha;                                                            \
        float ar[4];                                                           \
        _Pragma("unroll")                                                      \
        for (int r = 0; r < 4; r++) ar[r] = __shfl(alpha, grp * 4 + r);        \
        _Pragma("unroll")                                                      \
        for (int c = 0; c < 8; c++)                                            \
          _Pragma("unroll")                                                    \
          for (int r = 0; r < 4; r++) o[c][r] *= ar[r];                        \
      }                                                                        \
      const float msc = m * scl2;                                              \
      float p[2][4];                                                           \
      _Pragma("unroll")                                                        \
      for (int n = 0; n < 2; n++)                                              \
        _Pragma("unroll")                                                      \
        for (int r = 0; r < 4; r++)                                            \
          p[n][r] = exp2f(fmaf(s[n][r], scl2, -msc));                          \
      float rs = ((p[0][0] + p[0][1]) + (p[0][2] + p[0][3])) +                 \
                 ((p[1][0] + p[1][1]) + (p[1][2] + p[1][3]));                  \
      l += redsum4(rs);                                                        \
      u32 a0 = cvtpk(p[0][0], p[0][1]);                                        \
      u32 a1 = cvtpk(p[0][2], p[0][3]);                                        \
      u32 b0 = cvtpk(p[1][0], p[1][1]);                                        \
      u32 b1 = cvtpk(p[1][2], p[1][3]);                                        \
      asm volatile("v_permlane32_swap_b32 %0, %1" : "+v"(a0), "+v"(b0));       \
      asm volatile("v_permlane32_swap_b32 %0, %1" : "+v"(a1), "+v"(b1));       \
      asm volatile("v_permlane16_swap_b32 %0, %1" : "+v"(a0), "+v"(b0));       \
      asm volatile("v_permlane16_swap_b32 %0, %1" : "+v"(a1), "+v"(b1));       \
      union { bf16x8 v; u32 w[4]; } pau;                                       \
      pau.w[0] = a0; pau.w[1] = a1; pau.w[2] = b0; pau.w[3] = b1;              \
      bf16x8 pa = pau.v;                                                       \
      __builtin_amdgcn_s_setprio(1);                                           \
      _Pragma("unroll")                                                        \
      for (int c = 0; c < 8; c++) {                                            \
        bf16x8 vf = *(const bf16x8*)((const char*)Vs[CB] + va[c]);             \
        o[c] = __builtin_amdgcn_mfma_f32_16x16x32_bf16(pa, vf, o[c], 0, 0, 0); \
      }                                                                        \
      __builtin_amdgcn_s_setprio(0);                                           \
    }                                                                          \
    asm volatile("s_waitcnt lgkmcnt(0)" ::: "memory");                         \
    SCHED0();                                                                  \
    BAR();                                                                     \
    kp += 32 * 1024;                                                           \
    vp += 32;                                                                  \
  }

  for (int t = 0; t < nkv; t += 2) {
    ATTN_ITER(t, 0, 1);
    ATTN_ITER(t + 1, 1, 0);
  }
#undef ATTN_ITER

  // ---- epilogue ----
  float lr[4];
#pragma unroll
  for (int r = 0; r < 4; r++) lr[r] = 1.0f / __shfl(l, grp * 4 + r);
#pragma unroll
  for (int c = 0; c < 8; c++)
#pragma unroll
    for (int r = 0; r < 4; r++) {
      int qo = qrow0 + grp * 4 + r;
      float val = o[c][r] * lr[r];
      O[(size_t)(b * S_ + qo) * (NH_ * HD_) + h * HD_ + c * 16 + qloc] = f2b(val);
    }
}

// ---------------- launch ----------------
extern "C" void kernel_launch(void* const* d_in, const int* in_sizes, int n_in,
                              void* d_out, int out_size, void* d_ws, size_t ws_size,
                              hipStream_t stream) {
  const float* x  = (const float*)d_in[0];
  const float* wq = (const float*)d_in[1];
  const float* wk = (const float*)d_in[2];
  const float* wv = (const float*)d_in[3];
  const float* wo = (const float*)d_in[4];
  const float* fc = (const float*)d_in[5];
  const float* fs = (const float*)d_in[6];

  char* ws = (char*)d_ws;
  u16* Xb  = (u16*)(ws);                 // 33.5 MB  (later reused as Ow)
  u16* Wqb = (u16*)(ws + 33554432);      // 33.5 MB  (later reused as Wob)
  u16* Wkv = (u16*)(ws + 67108864);      // 16.8 MB  (K rows 0..1023, V rows 1024..2047)
  u16* Qw  = (u16*)(ws + 83886080);      // 33.5 MB
  u16* Kw  = (u16*)(ws + 117440512);     // 8.4 MB
  u16* Vw  = (u16*)(ws + 125829120);     // 8.4 MB  (V^T layout [1024][4096])
  u16* Ow  = Xb;
  u16* Wob = Wqb;

  auto cvt = [&](const float* in, u16* out, int n) {
    int n4 = n >> 2;
    int blocks = (n4 + 255) / 256; if (blocks > 2048) blocks = 2048;
    cvt_kernel<<<dim3(blocks), dim3(256), 0, stream>>>(in, out, n4);
  };
  cvt(x,  Xb,  B_ * S_ * DIM_);
  cvt(wq, Wqb, DIM_ * DIM_);
  cvt(wk, Wkv, NKV_ * HD_ * DIM_);
  cvt(wv, Wkv + (size_t)1024 * 4096, NKV_ * HD_ * DIM_);

  // Q-proj: 256x256 tiles, grid 256 (exact round)
  gemm256<0, false><<<dim3(16 * 16), 512, 0, stream>>>(Xb, Wqb, Qw, nullptr, 4096, 4096, 4096);
  // KV-proj: 128x256 tiles, grid 32*8 = 256 (exact round)
  gemm256<3, true><<<dim3(32 * 8), 512, 0, stream>>>(Xb, Wkv, Kw, Vw, 4096, 2048, 4096);

  cvt(wo, Wob, DIM_ * DIM_);

  rope_kernel<<<dim3((B_ * S_ * NKV_ * 64) / 256), 256, 0, stream>>>(Kw, fc, fs, NKV_);

  // attn: 128 q-rows/block, 8 waves, grid 1024 = 4 blocks/CU (r12 best config)
  attn_kernel<<<dim3(B_ * NH_ * (S_ / 128)), 512, 0, stream>>>(Qw, Kw, Vw, Ow, fc, fs);

  // O-proj: 256x256 tiles, grid 256 (exact round)
  gemm256<1, false><<<dim3(16 * 16), 512, 0, stream>>>(Ow, Wob, d_out, nullptr, 4096, 4096, 4096);
}

// Round 19
// 505.525 us; speedup vs baseline: 1.0045x; 1.0045x over previous
//
#include <hip/hip_runtime.h>

typedef unsigned short u16;
typedef unsigned int u32;
typedef __bf16 bf16_t;
typedef bf16_t bf16x8 __attribute__((ext_vector_type(8)));
typedef float f32x4 __attribute__((ext_vector_type(4)));

#define B_ 2
#define S_ 2048
#define DIM_ 4096
#define NH_ 32
#define NKV_ 8
#define HD_ 128

__device__ __forceinline__ u16 f2b(float f) {
  union { float f; unsigned u; } x; x.f = f;
  unsigned r = x.u + 0x7fffu + ((x.u >> 16) & 1u);
  return (u16)(r >> 16);
}
__device__ __forceinline__ float b2f(u16 u) {
  union { unsigned u; float f; } x; x.u = ((unsigned)u) << 16;
  return x.f;
}
__device__ __forceinline__ u32 cvtpk(float lo, float hi) {
  u32 r;
  asm volatile("v_cvt_pk_bf16_f32 %0, %1, %2" : "=v"(r) : "v"(lo), "v"(hi));
  return r;
}
// cross-lane reduce over lanes {l, l^16, l^32, l^48} — proven shfl_xor path
__device__ __forceinline__ float redmax4(float x) {
  x = fmaxf(x, __shfl_xor(x, 16));
  x = fmaxf(x, __shfl_xor(x, 32));
  return x;
}
__device__ __forceinline__ float redsum4(float x) {
  x += __shfl_xor(x, 16);
  x += __shfl_xor(x, 32);
  return x;
}

#define GLDS(gsrc, ldst) \
  __builtin_amdgcn_global_load_lds((const __attribute__((address_space(1))) void*)(gsrc), \
                                   (__attribute__((address_space(3))) void*)(ldst), 16, 0, 0)
#define BAR()    __builtin_amdgcn_s_barrier()
#define SCHED0() __builtin_amdgcn_sched_barrier(0)

// ---------------- f32 -> bf16 conversion ----------------
__global__ void cvt_kernel(const float* __restrict__ in, u16* __restrict__ out, int n4) {
  int i = blockIdx.x * blockDim.x + threadIdx.x;
  int stride = gridDim.x * blockDim.x;
  for (; i < n4; i += stride) {
    float4 v = ((const float4*)in)[i];
    ushort4 o;
    o.x = f2b(v.x); o.y = f2b(v.y); o.z = f2b(v.z); o.w = f2b(v.w);
    ((ushort4*)out)[i] = o;
  }
}

// ---------------- RoPE (in-place on bf16) — K only ----------------
__global__ void rope_kernel(u16* __restrict__ t, const float* __restrict__ fc,
                            const float* __restrict__ fs, int nheads) {
  int idx = blockIdx.x * blockDim.x + threadIdx.x;
  int ppr = nheads * 64;
  int row = idx / ppr;
  int pr = idx - row * ppr;
  int h = pr >> 6, j = pr & 63;
  int s = row & (S_ - 1);
  float c = fc[s * 64 + j], sn = fs[s * 64 + j];
  u16* p = t + (size_t)row * (size_t)(nheads * HD_) + h * HD_ + j * 2;
  float tr = b2f(p[0]), ti = b2f(p[1]);
  p[0] = f2b(tr * c - ti * sn);
  p[1] = f2b(tr * sn + ti * c);
}

// ---------------- 8-phase GEMM: C = A[M,K] * B[N,K]^T ----------------
// Tile = (SM ? 128 : 256) x 256, BK=64, 8 waves (2M x 4N), dbuf LDS, counted vmcnt.
// Barrier-reduced schedule (10 barriers/iter): per phase
//   [frag ds_reads; BAR; lgkmcnt(0); MFMA burst; stage (post-MFMA)]
// with the post-MFMA barrier kept ONLY at ph3/ph7 (after vmcnt(4)).
// MODE 0: bf16 row-major ld N; MODE 1: f32 row-major ld N;
// MODE 3: dual (col<1024 -> Cout bf16 ld 1024; col>=1024 -> Cout2 bf16 col-major [col-1024][M])
template<int MODE, bool SM>
__global__ __launch_bounds__(512, 2) void gemm256(const u16* __restrict__ A,
                                                  const u16* __restrict__ B,
                                                  void* __restrict__ Cout,
                                                  void* __restrict__ Cout2,
                                                  int M, int N, int K) {
  constexpr int BM = SM ? 128 : 256;
  constexpr int AH = SM ? 4096 : 8192;   // u16 per A-half
  constexpr int II = SM ? 1 : 2;         // m-frags per quadrant
  constexpr int NACC = SM ? 4 : 8;
  __shared__ u16 As[2][2][AH];
  __shared__ u16 Bs[2][2][8192];
  const int nbn = N >> 8;
  const int nwg = gridDim.x;
  int wg = blockIdx.x;
  wg = (wg & 7) * (nwg >> 3) + (wg >> 3);   // XCD swizzle (nwg % 8 == 0)
  const int bm = wg / nbn;
  const int bn = wg - bm * nbn;
  const int tid = threadIdx.x;
  const int lane = tid & 63;
  const int wv = tid >> 6;
  const int wm = wv >> 2, wn = wv & 3;
  const int qloc = lane & 15, grp = lane >> 4;
  const int NT = K >> 6;

  f32x4 acc[NACC][4];
#pragma unroll
  for (int i = 0; i < NACC; i++)
#pragma unroll
    for (int j = 0; j < 4; j++)
#pragma unroll
      for (int r = 0; r < 4; r++) acc[i][j][r] = 0.0f;

  const int srowl = lane >> 3;
  const int scsw = 8 * ((lane & 7) ^ srowl);   // pre-swizzled source col (elems)
  const size_t rowA = SM ? ((size_t)(bm * 128 + wv * 8 + srowl) * K + scsw)
                         : ((size_t)(bm * 256 + wv * 16 + srowl) * K + scsw);
  const size_t rowB = (size_t)(bn * 256 + wv * 16 + srowl) * K + scsw;

#define STAGE_A(buf, h, tt) { \
    if (SM) { \
      GLDS(A + rowA + (size_t)((h) * 64) * K + (size_t)(tt) * 64, &As[buf][h][wv * 512]); \
    } else { \
      GLDS(A + rowA + (size_t)((h) * 128) * K + (size_t)(tt) * 64, &As[buf][h][wv * 1024]); \
      GLDS(A + rowA + (size_t)((h) * 128 + 8) * K + (size_t)(tt) * 64, &As[buf][h][wv * 1024 + 512]); } }
#define STAGE_B(buf, h, tt) { \
    GLDS(B + rowB + (size_t)((h) * 128) * K + (size_t)(tt) * 64, &Bs[buf][h][wv * 1024]); \
    GLDS(B + rowB + (size_t)((h) * 128 + 8) * K + (size_t)(tt) * 64, &Bs[buf][h][wv * 1024 + 512]); }

  // ---- prologue: tile0 (A+B) into buf0, tile1 B into buf1 ----
  STAGE_A(0, 0, 0); STAGE_A(0, 1, 0);
  STAGE_B(0, 0, 0); STAGE_B(0, 1, 0);
  STAGE_B(1, 0, 1); STAGE_B(1, 1, 1);
  asm volatile("s_waitcnt vmcnt(4)" ::: "memory");   // tile0 fully landed
  BAR();

  for (int t = 0; t < NT; t += 2) {
#pragma unroll
    for (int half = 0; half < 2; half++) {
      bf16x8 bfr[4][2];
#pragma unroll
      for (int qd = 0; qd < 4; qd++) {
        if (qd == 0) {
#pragma unroll
          for (int j = 0; j < 4; j++)
#pragma unroll
            for (int ks = 0; ks < 2; ks++) {
              int rb = (wn & 1) * 64 + j * 16 + qloc;
              bfr[j][ks] = *(const bf16x8*)((const char*)&Bs[half][wn >> 1][0]
                           + rb * 128 + ((ks * 64 + grp * 16) ^ ((rb & 7) << 4)));
            }
        }
        bf16x8 af[II][2];
#pragma unroll
        for (int ii = 0; ii < II; ii++)
#pragma unroll
          for (int ks = 0; ks < 2; ks++) {
            int rh = SM ? (qd * 16 + qloc) : (qd * 32 + ii * 16 + qloc);
            af[ii][ks] = *(const bf16x8*)((const char*)&As[half][wm][0]
                         + rh * 128 + ((ks * 64 + grp * 16) ^ ((rh & 7) << 4)));
          }
        BAR();
        asm volatile("s_waitcnt lgkmcnt(0)" ::: "memory");
        SCHED0();
        __builtin_amdgcn_s_setprio(1);
#pragma unroll
        for (int ii = 0; ii < II; ii++)
#pragma unroll
          for (int ks = 0; ks < 2; ks++)
#pragma unroll
            for (int j = 0; j < 4; j++)
              acc[qd * II + ii][j] = __builtin_amdgcn_mfma_f32_16x16x32_bf16(
                  af[ii][ks], bfr[j][ks], acc[qd * II + ii][j], 0, 0, 0);
        __builtin_amdgcn_s_setprio(0);
        SCHED0();
        // ---- stage (post-MFMA; overlaps following phases' reads) ----
        const int ph = half * 4 + qd;
        if (ph == 0)      { STAGE_A(1, 0, t + 1); STAGE_A(1, 1, t + 1); }
        else if (ph == 1) { if (t + 2 < NT) { STAGE_B(0, 0, t + 2); STAGE_B(0, 1, t + 2); } }
        else if (ph == 4) { if (t + 2 < NT) { STAGE_A(0, 0, t + 2); STAGE_A(0, 1, t + 2); } }
        else if (ph == 5) { if (t + 3 < NT) { STAGE_B(1, 0, t + 3); STAGE_B(1, 1, t + 3); } }
        if (qd == 3) {
          if ((half == 0 ? t + 2 : t + 3) < NT)
            asm volatile("s_waitcnt vmcnt(4)" ::: "memory");
          else
            asm volatile("s_waitcnt vmcnt(0)" ::: "memory");
          BAR();
        }
      }
    }
  }
#undef STAGE_A
#undef STAGE_B

  // ---- epilogue ----
  const int r0g = bm * BM + wm * (BM / 2) + grp * 4;
  const int c0g = bn * 256 + wn * 64 + qloc;
#pragma unroll
  for (int i = 0; i < NACC; i++)
#pragma unroll
    for (int j = 0; j < 4; j++)
#pragma unroll
      for (int r = 0; r < 4; r++) {
        int row = r0g + i * 16 + r;
        int col = c0g + j * 16;
        float v = acc[i][j][r];
        if (MODE == 1)      ((float*)Cout)[(size_t)row * N + col] = v;
        else if (MODE == 0) ((u16*)Cout)[(size_t)row * N + col]  = f2b(v);
        else {
          if (col < 1024) ((u16*)Cout)[(size_t)row * 1024 + col] = f2b(v);
          else            ((u16*)Cout2)[(size_t)(col - 1024) * M + row] = f2b(v);
        }
      }
}

// ---------------- Flash attention (causal, GQA 4:1) ----------------
// r12 config: block = 128 q rows; 8 waves x 16 q; KV tile = 32, dbuf; grid 1024.
// r17/r18 post-mortem: module-level regalloc perturbation (rule #19) moved the
// QK^T scores into AGPRs -> v_accvgpr copies on every softmax op (+33 us).
// Fix: empty inline-asm "+v" constraint on s[0..1] right after the QK^T burst
// forces the scores into arch VGPRs (zero-instruction cost). o[] stays AGPR
// (touched only on rare rescale + epilogue) which is the desirable placement.
__global__ __launch_bounds__(512, 4) void attn_kernel(const u16* __restrict__ Q,
                                                      const u16* __restrict__ Kt,
                                                      const u16* __restrict__ VT,
                                                      u16* __restrict__ O,
                                                      const float* __restrict__ fc,
                                                      const float* __restrict__ fs) {
  __shared__ u16 Ks[2][32 * 128];
  __shared__ u16 Vs[2][32 * 128];

  const int bid = blockIdx.x;
  const int qb = 15 - (bid >> 6);        // heavy blocks first (128-row q blocks)
  const int h = bid & 31;
  const int b = (bid >> 5) & 1;
  const int g = h >> 2;
  const int tid = threadIdx.x;
  const int lane = tid & 63;
  const int wv = tid >> 6;               // 0..7
  const int qrow0 = qb * 128 + wv * 16;
  const float scl2 = 0.12751744f;        // (1/sqrt(128)) * log2(e)

  const int qloc = lane & 15;
  const int grp = lane >> 4;

  // ---- Q fragment with fused RoPE ----
  bf16x8 qf[4];
  {
    const int qr = qrow0 + qloc;
    const u16* qptr = Q + (size_t)(b * S_ + qr) * (NH_ * HD_) + h * HD_ + grp * 8;
#pragma unroll
    for (int c = 0; c < 4; c++) {
      union { bf16x8 v; u16 u[8]; } raw;
      raw.v = *(const bf16x8*)(qptr + c * 32);
      const int p0 = c * 16 + grp * 4;
      const float4 cv = *(const float4*)&fc[(size_t)qr * 64 + p0];
      const float4 sv = *(const float4*)&fs[(size_t)qr * 64 + p0];
      union { bf16x8 v; u32 w[4]; } out;
      const float cc[4] = {cv.x, cv.y, cv.z, cv.w};
      const float ss[4] = {sv.x, sv.y, sv.z, sv.w};
#pragma unroll
      for (int j = 0; j < 4; j++) {
        float tr = b2f(raw.u[2 * j]), ti = b2f(raw.u[2 * j + 1]);
        out.w[j] = cvtpk(tr * cc[j] - ti * ss[j], tr * ss[j] + ti * cc[j]);
      }
      qf[c] = out.v;
    }
  }

  float m = -1e30f, l = 0.f;
  f32x4 o[8];
#pragma unroll
  for (int c = 0; c < 8; c++)
#pragma unroll
    for (int r = 0; r < 4; r++) o[c][r] = 0.f;

  const int nkv = 4 * qb + 4;            // tiles of 32 keys; always even

  // ---- loop-invariant LDS read byte-offsets ----
  int ka[2][4];
#pragma unroll
  for (int n = 0; n < 2; n++)
#pragma unroll
    for (int c = 0; c < 4; c++) {
      int krow = n * 16 + qloc;
      ka[n][c] = krow * 256 + ((c * 64 + grp * 16) ^ ((krow & 7) << 4));
    }
  int va[8];
#pragma unroll
  for (int c = 0; c < 8; c++) {
    int d = c * 16 + qloc;
    va[c] = d * 64 + ((grp * 16) ^ (((d >> 1) & 3) << 4));
  }

  // ---- staging geometry: 8 waves cover the 32x128 K tile & 128x32 V^T tile ----
  const int kkey = wv * 4 + grp;
  const int cbsK = (qloc * 16) ^ ((kkey & 7) << 4);
  const int vd = wv * 16 + (lane >> 2);
  const int kbsV = ((lane & 3) * 16) ^ (((vd >> 1) & 3) << 4);

  const u16* kp = Kt + (size_t)(b * S_ + kkey) * 1024 + g * HD_ + (cbsK >> 1);
  const u16* vp = VT + (size_t)(g * HD_ + vd) * 4096 + (size_t)b * S_ + (kbsV >> 1);

  // prologue: stage tile 0 into buf 0
  GLDS(kp, &Ks[0][wv * 512]);
  GLDS(vp, &Vs[0][wv * 512]);
  kp += 32 * 1024;   // -> tile 1
  vp += 32;

#define ATTN_ITER(T, CB, NB)                                                   \
  {                                                                            \
    const bool pf = ((T) + 1 < nkv);                                           \
    if (pf) {                                                                  \
      GLDS(kp, &Ks[NB][wv * 512]);                                             \
      GLDS(vp, &Vs[NB][wv * 512]);                                             \
      asm volatile("s_waitcnt vmcnt(2)" ::: "memory");                         \
    } else {                                                                   \
      asm volatile("s_waitcnt vmcnt(0)" ::: "memory");                         \
    }                                                                          \
    BAR();                                                                     \
    SCHED0();                                                                  \
    if ((T) * 32 <= qrow0 + 15) {                                              \
      f32x4 s[2];                                                              \
      __builtin_amdgcn_s_setprio(1);                                           \
      _Pragma("unroll")                                                        \
      for (int n = 0; n < 2; n++) {                                            \
        f32x4 sc;                                                              \
        _Pragma("unroll")                                                      \
        for (int r = 0; r < 4; r++) sc[r] = 0.f;                               \
        _Pragma("unroll")                                                      \
        for (int c = 0; c < 4; c++) {                                          \
          bf16x8 kf = *(const bf16x8*)((const char*)Ks[CB] + ka[n][c]);        \
          sc = __builtin_amdgcn_mfma_f32_16x16x32_bf16(kf, qf[c], sc, 0, 0, 0);\
        }                                                                      \
        s[n] = sc;                                                             \
      }                                                                        \
      __builtin_amdgcn_s_setprio(0);                                           \
      /* force scores into arch VGPRs (kill AGPR<->VGPR copy chain, rule #19) */\
      asm volatile("" : "+v"(s[0]), "+v"(s[1]));                               \
      const int q = qrow0 + qloc;                                              \
      if ((T) * 32 + 31 > qrow0) {                                             \
        _Pragma("unroll")                                                      \
        for (int n = 0; n < 2; n++)                                            \
          _Pragma("unroll")                                                    \
          for (int r = 0; r < 4; r++) {                                        \
            int k = (T) * 32 + n * 16 + grp * 4 + r;                           \
            if (k > q) s[n][r] = -1e9f;                                        \
          }                                                                    \
      }                                                                        \
      float pmax = fmaxf(fmaxf(fmaxf(s[0][0], s[0][1]), fmaxf(s[0][2], s[0][3])), \
                         fmaxf(fmaxf(s[1][0], s[1][1]), fmaxf(s[1][2], s[1][3]))); \
      pmax = redmax4(pmax);                                                    \
      if (__any(pmax > m + 64.f)) {                                            \
        float mn = fmaxf(m, pmax);                                             \
        float alpha = exp2f((m - mn) * scl2);                                  \
        m = mn;                                                                \
        l *= alpha;                                                            \
        float ar[4];                                                           \
        _Pragma("unroll")                                                      \
        for (int r = 0; r < 4; r++) ar[r] = __shfl(alpha, grp * 4 + r);        \
        _Pragma("unroll")                                                      \
        for (int c = 0; c < 8; c++)                                            \
          _Pragma("unroll")                                                    \
          for (int r = 0; r < 4; r++) o[c][r] *= ar[r];                        \
      }                                                                        \
      const float msc = m * scl2;                                              \
      float p[2][4];                                                           \
      _Pragma("unroll")                                                        \
      for (int n = 0; n < 2; n++)                                              \
        _Pragma("unroll")                                                      \
        for (int r = 0; r < 4; r++)                                            \
          p[n][r] = exp2f(fmaf(s[n][r], scl2, -msc));                          \
      float rs = ((p[0][0] + p[0][1]) + (p[0][2] + p[0][3])) +                 \
                 ((p[1][0] + p[1][1]) + (p[1][2] + p[1][3]));                  \
      l += redsum4(rs);                                                        \
      u32 a0 = cvtpk(p[0][0], p[0][1]);                                        \
      u32 a1 = cvtpk(p[0][2], p[0][3]);                                        \
      u32 b0 = cvtpk(p[1][0], p[1][1]);                                        \
      u32 b1 = cvtpk(p[1][2], p[1][3]);                                        \
      asm volatile("v_permlane32_swap_b32 %0, %1" : "+v"(a0), "+v"(b0));       \
      asm volatile("v_permlane32_swap_b32 %0, %1" : "+v"(a1), "+v"(b1));       \
      asm volatile("v_permlane16_swap_b32 %0, %1" : "+v"(a0), "+v"(b0));       \
      asm volatile("v_permlane16_swap_b32 %0, %1" : "+v"(a1), "+v"(b1));       \
      union { bf16x8 v; u32 w[4]; } pau;                                       \
      pau.w[0] = a0; pau.w[1] = a1; pau.w[2] = b0; pau.w[3] = b1;              \
      bf16x8 pa = pau.v;                                                       \
      __builtin_amdgcn_s_setprio(1);                                           \
      _Pragma("unroll")                                                        \
      for (int c = 0; c < 8; c++) {                                            \
        bf16x8 vf = *(const bf16x8*)((const char*)Vs[CB] + va[c]);             \
        o[c] = __builtin_amdgcn_mfma_f32_16x16x32_bf16(pa, vf, o[c], 0, 0, 0); \
      }                                                                        \
      __builtin_amdgcn_s_setprio(0);                                           \
    }                                                                          \
    asm volatile("s_waitcnt lgkmcnt(0)" ::: "memory");                         \
    SCHED0();                                                                  \
    BAR();                                                                     \
    kp += 32 * 1024;                                                           \
    vp += 32;                                                                  \
  }

  for (int t = 0; t < nkv; t += 2) {
    ATTN_ITER(t, 0, 1);
    ATTN_ITER(t + 1, 1, 0);
  }
#undef ATTN_ITER

  // ---- epilogue ----
  float lr[4];
#pragma unroll
  for (int r = 0; r < 4; r++) lr[r] = 1.0f / __shfl(l, grp * 4 + r);
#pragma unroll
  for (int c = 0; c < 8; c++)
#pragma unroll
    for (int r = 0; r < 4; r++) {
      int qo = qrow0 + grp * 4 + r;
      float val = o[c][r] * lr[r];
      O[(size_t)(b * S_ + qo) * (NH_ * HD_) + h * HD_ + c * 16 + qloc] = f2b(val);
    }
}

// ---------------- launch ----------------
extern "C" void kernel_launch(void* const* d_in, const int* in_sizes, int n_in,
                              void* d_out, int out_size, void* d_ws, size_t ws_size,
                              hipStream_t stream) {
  const float* x  = (const float*)d_in[0];
  const float* wq = (const float*)d_in[1];
  const float* wk = (const float*)d_in[2];
  const float* wv = (const float*)d_in[3];
  const float* wo = (const float*)d_in[4];
  const float* fc = (const float*)d_in[5];
  const float* fs = (const float*)d_in[6];

  char* ws = (char*)d_ws;
  u16* Xb  = (u16*)(ws);                 // 33.5 MB  (later reused as Ow)
  u16* Wqb = (u16*)(ws + 33554432);      // 33.5 MB  (later reused as Wob)
  u16* Wkv = (u16*)(ws + 67108864);      // 16.8 MB  (K rows 0..1023, V rows 1024..2047)
  u16* Qw  = (u16*)(ws + 83886080);      // 33.5 MB
  u16* Kw  = (u16*)(ws + 117440512);     // 8.4 MB
  u16* Vw  = (u16*)(ws + 125829120);     // 8.4 MB  (V^T layout [1024][4096])
  u16* Ow  = Xb;
  u16* Wob = Wqb;

  auto cvt = [&](const float* in, u16* out, int n) {
    int n4 = n >> 2;
    int blocks = (n4 + 255) / 256; if (blocks > 2048) blocks = 2048;
    cvt_kernel<<<dim3(blocks), dim3(256), 0, stream>>>(in, out, n4);
  };
  cvt(x,  Xb,  B_ * S_ * DIM_);
  cvt(wq, Wqb, DIM_ * DIM_);
  cvt(wk, Wkv, NKV_ * HD_ * DIM_);
  cvt(wv, Wkv + (size_t)1024 * 4096, NKV_ * HD_ * DIM_);

  // Q-proj: 256x256 tiles, grid 256 (exact round)
  gemm256<0, false><<<dim3(16 * 16), 512, 0, stream>>>(Xb, Wqb, Qw, nullptr, 4096, 4096, 4096);
  // KV-proj: 128x256 tiles, grid 32*8 = 256 (exact round)
  gemm256<3, true><<<dim3(32 * 8), 512, 0, stream>>>(Xb, Wkv, Kw, Vw, 4096, 2048, 4096);

  cvt(wo, Wob, DIM_ * DIM_);

  rope_kernel<<<dim3((B_ * S_ * NKV_ * 64) / 256), 256, 0, stream>>>(Kw, fc, fs, NKV_);

  // attn: 128 q-rows/block, 8 waves, grid 1024 = 4 blocks/CU (r12 best config)
  attn_kernel<<<dim3(B_ * NH_ * (S_ / 128)), 512, 0, stream>>>(Qw, Kw, Vw, Ow, fc, fs);

  // O-proj: 256x256 tiles, grid 256 (exact round)
  gemm256<1, false><<<dim3(16 * 16), 512, 0, stream>>>(Ow, Wob, d_out, nullptr, 4096, 4096, 4096);
}

// Round 20
// 505.518 us; speedup vs baseline: 1.0045x; 1.0000x over previous
//
#include <hip/hip_runtime.h>

typedef unsigned short u16;
typedef unsigned int u32;
typedef __bf16 bf16_t;
typedef bf16_t bf16x8 __attribute__((ext_vector_type(8)));
typedef float f32x4 __attribute__((ext_vector_type(4)));

#define B_ 2
#define S_ 2048
#define DIM_ 4096
#define NH_ 32
#define NKV_ 8
#define HD_ 128

__device__ __forceinline__ u16 f2b(float f) {
  union { float f; unsigned u; } x; x.f = f;
  unsigned r = x.u + 0x7fffu + ((x.u >> 16) & 1u);
  return (u16)(r >> 16);
}
__device__ __forceinline__ float b2f(u16 u) {
  union { unsigned u; float f; } x; x.u = ((unsigned)u) << 16;
  return x.f;
}
__device__ __forceinline__ u32 cvtpk(float lo, float hi) {
  u32 r;
  asm volatile("v_cvt_pk_bf16_f32 %0, %1, %2" : "=v"(r) : "v"(lo), "v"(hi));
  return r;
}
// cross-lane reduce over lanes {l, l^16, l^32, l^48} — proven shfl_xor path
__device__ __forceinline__ float redmax4(float x) {
  x = fmaxf(x, __shfl_xor(x, 16));
  x = fmaxf(x, __shfl_xor(x, 32));
  return x;
}
__device__ __forceinline__ float redsum4(float x) {
  x += __shfl_xor(x, 16);
  x += __shfl_xor(x, 32);
  return x;
}

#define GLDS(gsrc, ldst) \
  __builtin_amdgcn_global_load_lds((const __attribute__((address_space(1))) void*)(gsrc), \
                                   (__attribute__((address_space(3))) void*)(ldst), 16, 0, 0)
#define BAR()    __builtin_amdgcn_s_barrier()
#define SCHED0() __builtin_amdgcn_sched_barrier(0)

// ---------------- f32 -> bf16 conversion ----------------
__global__ void cvt_kernel(const float* __restrict__ in, u16* __restrict__ out, int n4) {
  int i = blockIdx.x * blockDim.x + threadIdx.x;
  int stride = gridDim.x * blockDim.x;
  for (; i < n4; i += stride) {
    float4 v = ((const float4*)in)[i];
    ushort4 o;
    o.x = f2b(v.x); o.y = f2b(v.y); o.z = f2b(v.z); o.w = f2b(v.w);
    ((ushort4*)out)[i] = o;
  }
}

// ---------------- RoPE (in-place on bf16) — K only ----------------
__global__ void rope_kernel(u16* __restrict__ t, const float* __restrict__ fc,
                            const float* __restrict__ fs, int nheads) {
  int idx = blockIdx.x * blockDim.x + threadIdx.x;
  int ppr = nheads * 64;
  int row = idx / ppr;
  int pr = idx - row * ppr;
  int h = pr >> 6, j = pr & 63;
  int s = row & (S_ - 1);
  float c = fc[s * 64 + j], sn = fs[s * 64 + j];
  u16* p = t + (size_t)row * (size_t)(nheads * HD_) + h * HD_ + j * 2;
  float tr = b2f(p[0]), ti = b2f(p[1]);
  p[0] = f2b(tr * c - ti * sn);
  p[1] = f2b(tr * sn + ti * c);
}

// ---------------- Flash attention (causal, GQA 4:1) ----------------
// Defined BEFORE gemm256: r17 showed that changing gemm256's body flipped this
// kernel's codegen (VGPR 64->44, AGPR traffic, +39 us) with attn source
// byte-identical — rule #19 module-level regalloc coupling. Emitting attn
// first restores the compilation context of the fast (r15/r16) binary.
// Config: block = 128 q rows; 8 waves x 16 q; KV tile = 32, dbuf; grid 1024.
__global__ __launch_bounds__(512) void attn_kernel(const u16* __restrict__ Q,
                                                   const u16* __restrict__ Kt,
                                                   const u16* __restrict__ VT,
                                                   u16* __restrict__ O,
                                                   const float* __restrict__ fc,
                                                   const float* __restrict__ fs) {
  __shared__ u16 Ks[2][32 * 128];
  __shared__ u16 Vs[2][32 * 128];

  const int bid = blockIdx.x;
  const int qb = 15 - (bid >> 6);        // heavy blocks first (128-row q blocks)
  const int h = bid & 31;
  const int b = (bid >> 5) & 1;
  const int g = h >> 2;
  const int tid = threadIdx.x;
  const int lane = tid & 63;
  const int wv = tid >> 6;               // 0..7
  const int qrow0 = qb * 128 + wv * 16;
  const float scl2 = 0.12751744f;        // (1/sqrt(128)) * log2(e)

  const int qloc = lane & 15;
  const int grp = lane >> 4;

  // ---- Q fragment with fused RoPE ----
  bf16x8 qf[4];
  {
    const int qr = qrow0 + qloc;
    const u16* qptr = Q + (size_t)(b * S_ + qr) * (NH_ * HD_) + h * HD_ + grp * 8;
#pragma unroll
    for (int c = 0; c < 4; c++) {
      union { bf16x8 v; u16 u[8]; } raw;
      raw.v = *(const bf16x8*)(qptr + c * 32);
      const int p0 = c * 16 + grp * 4;
      const float4 cv = *(const float4*)&fc[(size_t)qr * 64 + p0];
      const float4 sv = *(const float4*)&fs[(size_t)qr * 64 + p0];
      union { bf16x8 v; u32 w[4]; } out;
      const float cc[4] = {cv.x, cv.y, cv.z, cv.w};
      const float ss[4] = {sv.x, sv.y, sv.z, sv.w};
#pragma unroll
      for (int j = 0; j < 4; j++) {
        float tr = b2f(raw.u[2 * j]), ti = b2f(raw.u[2 * j + 1]);
        out.w[j] = cvtpk(tr * cc[j] - ti * ss[j], tr * ss[j] + ti * cc[j]);
      }
      qf[c] = out.v;
    }
  }

  float m = -1e30f, l = 0.f;
  f32x4 o[8];
#pragma unroll
  for (int c = 0; c < 8; c++)
#pragma unroll
    for (int r = 0; r < 4; r++) o[c][r] = 0.f;

  const int nkv = 4 * qb + 4;            // tiles of 32 keys; always even

  // ---- loop-invariant LDS read byte-offsets ----
  int ka[2][4];
#pragma unroll
  for (int n = 0; n < 2; n++)
#pragma unroll
    for (int c = 0; c < 4; c++) {
      int krow = n * 16 + qloc;
      ka[n][c] = krow * 256 + ((c * 64 + grp * 16) ^ ((krow & 7) << 4));
    }
  int va[8];
#pragma unroll
  for (int c = 0; c < 8; c++) {
    int d = c * 16 + qloc;
    va[c] = d * 64 + ((grp * 16) ^ (((d >> 1) & 3) << 4));
  }

  // ---- staging geometry: 8 waves cover the 32x128 K tile & 128x32 V^T tile ----
  const int kkey = wv * 4 + grp;
  const int cbsK = (qloc * 16) ^ ((kkey & 7) << 4);
  const int vd = wv * 16 + (lane >> 2);
  const int kbsV = ((lane & 3) * 16) ^ (((vd >> 1) & 3) << 4);

  const u16* kp = Kt + (size_t)(b * S_ + kkey) * 1024 + g * HD_ + (cbsK >> 1);
  const u16* vp = VT + (size_t)(g * HD_ + vd) * 4096 + (size_t)b * S_ + (kbsV >> 1);

  // prologue: stage tile 0 into buf 0
  GLDS(kp, &Ks[0][wv * 512]);
  GLDS(vp, &Vs[0][wv * 512]);
  kp += 32 * 1024;   // -> tile 1
  vp += 32;

#define ATTN_ITER(T, CB, NB)                                                   \
  {                                                                            \
    const bool pf = ((T) + 1 < nkv);                                           \
    if (pf) {                                                                  \
      GLDS(kp, &Ks[NB][wv * 512]);                                             \
      GLDS(vp, &Vs[NB][wv * 512]);                                             \
      asm volatile("s_waitcnt vmcnt(2)" ::: "memory");                         \
    } else {                                                                   \
      asm volatile("s_waitcnt vmcnt(0)" ::: "memory");                         \
    }                                                                          \
    BAR();                                                                     \
    SCHED0();                                                                  \
    if ((T) * 32 <= qrow0 + 15) {                                              \
      f32x4 s[2];                                                              \
      __builtin_amdgcn_s_setprio(1);                                           \
      _Pragma("unroll")                                                        \
      for (int n = 0; n < 2; n++) {                                            \
        f32x4 sc;                                                              \
        _Pragma("unroll")                                                      \
        for (int r = 0; r < 4; r++) sc[r] = 0.f;                               \
        _Pragma("unroll")                                                      \
        for (int c = 0; c < 4; c++) {                                          \
          bf16x8 kf = *(const bf16x8*)((const char*)Ks[CB] + ka[n][c]);        \
          sc = __builtin_amdgcn_mfma_f32_16x16x32_bf16(kf, qf[c], sc, 0, 0, 0);\
        }                                                                      \
        s[n] = sc;                                                             \
      }                                                                        \
      __builtin_amdgcn_s_setprio(0);                                           \
      const int q = qrow0 + qloc;                                              \
      if ((T) * 32 + 31 > qrow0) {                                             \
        _Pragma("unroll")                                                      \
        for (int n = 0; n < 2; n++)                                            \
          _Pragma("unroll")                                                    \
          for (int r = 0; r < 4; r++) {                                        \
            int k = (T) * 32 + n * 16 + grp * 4 + r;                           \
            if (k > q) s[n][r] = -1e9f;                                        \
          }                                                                    \
      }                                                                        \
      float pmax = fmaxf(fmaxf(fmaxf(s[0][0], s[0][1]), fmaxf(s[0][2], s[0][3])), \
                         fmaxf(fmaxf(s[1][0], s[1][1]), fmaxf(s[1][2], s[1][3]))); \
      pmax = redmax4(pmax);                                                    \
      if (__any(pmax > m + 64.f)) {                                            \
        float mn = fmaxf(m, pmax);                                             \
        float alpha = exp2f((m - mn) * scl2);                                  \
        m = mn;                                                                \
        l *= alpha;                                                            \
        float ar[4];                                                           \
        _Pragma("unroll")                                                      \
        for (int r = 0; r < 4; r++) ar[r] = __shfl(alpha, grp * 4 + r);        \
        _Pragma("unroll")                                                      \
        for (int c = 0; c < 8; c++)                                            \
          _Pragma("unroll")                                                    \
          for (int r = 0; r < 4; r++) o[c][r] *= ar[r];                        \
      }                                                                        \
      const float msc = m * scl2;                                              \
      float p[2][4];                                                           \
      _Pragma("unroll")                                                        \
      for (int n = 0; n < 2; n++)                                              \
        _Pragma("unroll")                                                      \
        for (int r = 0; r < 4; r++)                                            \
          p[n][r] = exp2f(fmaf(s[n][r], scl2, -msc));                          \
      float rs = ((p[0][0] + p[0][1]) + (p[0][2] + p[0][3])) +                 \
                 ((p[1][0] + p[1][1]) + (p[1][2] + p[1][3]));                  \
      l += redsum4(rs);                                                        \
      u32 a0 = cvtpk(p[0][0], p[0][1]);                                        \
      u32 a1 = cvtpk(p[0][2], p[0][3]);                                        \
      u32 b0 = cvtpk(p[1][0], p[1][1]);                                        \
      u32 b1 = cvtpk(p[1][2], p[1][3]);                                        \
      asm volatile("v_permlane32_swap_b32 %0, %1" : "+v"(a0), "+v"(b0));       \
      asm volatile("v_permlane32_swap_b32 %0, %1" : "+v"(a1), "+v"(b1));       \
      asm volatile("v_permlane16_swap_b32 %0, %1" : "+v"(a0), "+v"(b0));       \
      asm volatile("v_permlane16_swap_b32 %0, %1" : "+v"(a1), "+v"(b1));       \
      union { bf16x8 v; u32 w[4]; } pau;                                       \
      pau.w[0] = a0; pau.w[1] = a1; pau.w[2] = b0; pau.w[3] = b1;              \
      bf16x8 pa = pau.v;                                                       \
      __builtin_amdgcn_s_setprio(1);                                           \
      _Pragma("unroll")                                                        \
      for (int c = 0; c < 8; c++) {                                            \
        bf16x8 vf = *(const bf16x8*)((const char*)Vs[CB] + va[c]);             \
        o[c] = __builtin_amdgcn_mfma_f32_16x16x32_bf16(pa, vf, o[c], 0, 0, 0); \
      }                                                                        \
      __builtin_amdgcn_s_setprio(0);                                           \
    }                                                                          \
    asm volatile("s_waitcnt lgkmcnt(0)" ::: "memory");                         \
    SCHED0();                                                                  \
    BAR();                                                                     \
    kp += 32 * 1024;                                                           \
    vp += 32;                                                                  \
  }

  for (int t = 0; t < nkv; t += 2) {
    ATTN_ITER(t, 0, 1);
    ATTN_ITER(t + 1, 1, 0);
  }
#undef ATTN_ITER

  // ---- epilogue ----
  float lr[4];
#pragma unroll
  for (int r = 0; r < 4; r++) lr[r] = 1.0f / __shfl(l, grp * 4 + r);
#pragma unroll
  for (int c = 0; c < 8; c++)
#pragma unroll
    for (int r = 0; r < 4; r++) {
      int qo = qrow0 + grp * 4 + r;
      float val = o[c][r] * lr[r];
      O[(size_t)(b * S_ + qo) * (NH_ * HD_) + h * HD_ + c * 16 + qloc] = f2b(val);
    }
}

// ---------------- 8-phase GEMM: C = A[M,K] * B[N,K]^T ----------------
// Tile = (SM ? 128 : 256) x 256, BK=64, 8 waves (2M x 4N), dbuf LDS, counted vmcnt.
// Barrier-reduced schedule (10 barriers/iter): per phase
//   [frag ds_reads; BAR; lgkmcnt(0); MFMA burst; stage (post-MFMA)]
// with the post-MFMA barrier kept ONLY at ph3/ph7 (after vmcnt(4)).
// MODE 0: bf16 row-major ld N; MODE 1: f32 row-major ld N;
// MODE 3: dual (col<1024 -> Cout bf16 ld 1024; col>=1024 -> Cout2 bf16 col-major [col-1024][M])
template<int MODE, bool SM>
__global__ __launch_bounds__(512, 2) void gemm256(const u16* __restrict__ A,
                                                  const u16* __restrict__ B,
                                                  void* __restrict__ Cout,
                                                  void* __restrict__ Cout2,
                                                  int M, int N, int K) {
  constexpr int BM = SM ? 128 : 256;
  constexpr int AH = SM ? 4096 : 8192;   // u16 per A-half
  constexpr int II = SM ? 1 : 2;         // m-frags per quadrant
  constexpr int NACC = SM ? 4 : 8;
  __shared__ u16 As[2][2][AH];
  __shared__ u16 Bs[2][2][8192];
  const int nbn = N >> 8;
  const int nwg = gridDim.x;
  int wg = blockIdx.x;
  wg = (wg & 7) * (nwg >> 3) + (wg >> 3);   // XCD swizzle (nwg % 8 == 0)
  const int bm = wg / nbn;
  const int bn = wg - bm * nbn;
  const int tid = threadIdx.x;
  const int lane = tid & 63;
  const int wv = tid >> 6;
  const int wm = wv >> 2, wn = wv & 3;
  const int qloc = lane & 15, grp = lane >> 4;
  const int NT = K >> 6;

  f32x4 acc[NACC][4];
#pragma unroll
  for (int i = 0; i < NACC; i++)
#pragma unroll
    for (int j = 0; j < 4; j++)
#pragma unroll
      for (int r = 0; r < 4; r++) acc[i][j][r] = 0.0f;

  const int srowl = lane >> 3;
  const int scsw = 8 * ((lane & 7) ^ srowl);   // pre-swizzled source col (elems)
  const size_t rowA = SM ? ((size_t)(bm * 128 + wv * 8 + srowl) * K + scsw)
                         : ((size_t)(bm * 256 + wv * 16 + srowl) * K + scsw);
  const size_t rowB = (size_t)(bn * 256 + wv * 16 + srowl) * K + scsw;

#define STAGE_A(buf, h, tt) { \
    if (SM) { \
      GLDS(A + rowA + (size_t)((h) * 64) * K + (size_t)(tt) * 64, &As[buf][h][wv * 512]); \
    } else { \
      GLDS(A + rowA + (size_t)((h) * 128) * K + (size_t)(tt) * 64, &As[buf][h][wv * 1024]); \
      GLDS(A + rowA + (size_t)((h) * 128 + 8) * K + (size_t)(tt) * 64, &As[buf][h][wv * 1024 + 512]); } }
#define STAGE_B(buf, h, tt) { \
    GLDS(B + rowB + (size_t)((h) * 128) * K + (size_t)(tt) * 64, &Bs[buf][h][wv * 1024]); \
    GLDS(B + rowB + (size_t)((h) * 128 + 8) * K + (size_t)(tt) * 64, &Bs[buf][h][wv * 1024 + 512]); }

  // ---- prologue: tile0 (A+B) into buf0, tile1 B into buf1 ----
  STAGE_A(0, 0, 0); STAGE_A(0, 1, 0);
  STAGE_B(0, 0, 0); STAGE_B(0, 1, 0);
  STAGE_B(1, 0, 1); STAGE_B(1, 1, 1);
  asm volatile("s_waitcnt vmcnt(4)" ::: "memory");   // tile0 fully landed
  BAR();

  for (int t = 0; t < NT; t += 2) {
#pragma unroll
    for (int half = 0; half < 2; half++) {
      bf16x8 bfr[4][2];
#pragma unroll
      for (int qd = 0; qd < 4; qd++) {
        if (qd == 0) {
#pragma unroll
          for (int j = 0; j < 4; j++)
#pragma unroll
            for (int ks = 0; ks < 2; ks++) {
              int rb = (wn & 1) * 64 + j * 16 + qloc;
              bfr[j][ks] = *(const bf16x8*)((const char*)&Bs[half][wn >> 1][0]
                           + rb * 128 + ((ks * 64 + grp * 16) ^ ((rb & 7) << 4)));
            }
        }
        bf16x8 af[II][2];
#pragma unroll
        for (int ii = 0; ii < II; ii++)
#pragma unroll
          for (int ks = 0; ks < 2; ks++) {
            int rh = SM ? (qd * 16 + qloc) : (qd * 32 + ii * 16 + qloc);
            af[ii][ks] = *(const bf16x8*)((const char*)&As[half][wm][0]
                         + rh * 128 + ((ks * 64 + grp * 16) ^ ((rh & 7) << 4)));
          }
        BAR();
        asm volatile("s_waitcnt lgkmcnt(0)" ::: "memory");
        SCHED0();
        __builtin_amdgcn_s_setprio(1);
#pragma unroll
        for (int ii = 0; ii < II; ii++)
#pragma unroll
          for (int ks = 0; ks < 2; ks++)
#pragma unroll
            for (int j = 0; j < 4; j++)
              acc[qd * II + ii][j] = __builtin_amdgcn_mfma_f32_16x16x32_bf16(
                  af[ii][ks], bfr[j][ks], acc[qd * II + ii][j], 0, 0, 0);
        __builtin_amdgcn_s_setprio(0);
        SCHED0();
        // ---- stage (post-MFMA; overlaps following phases' reads) ----
        const int ph = half * 4 + qd;
        if (ph == 0)      { STAGE_A(1, 0, t + 1); STAGE_A(1, 1, t + 1); }
        else if (ph == 1) { if (t + 2 < NT) { STAGE_B(0, 0, t + 2); STAGE_B(0, 1, t + 2); } }
        else if (ph == 4) { if (t + 2 < NT) { STAGE_A(0, 0, t + 2); STAGE_A(0, 1, t + 2); } }
        else if (ph == 5) { if (t + 3 < NT) { STAGE_B(1, 0, t + 3); STAGE_B(1, 1, t + 3); } }
        if (qd == 3) {
          if ((half == 0 ? t + 2 : t + 3) < NT)
            asm volatile("s_waitcnt vmcnt(4)" ::: "memory");
          else
            asm volatile("s_waitcnt vmcnt(0)" ::: "memory");
          BAR();
        }
      }
    }
  }
#undef STAGE_A
#undef STAGE_B

  // ---- epilogue ----
  const int r0g = bm * BM + wm * (BM / 2) + grp * 4;
  const int c0g = bn * 256 + wn * 64 + qloc;
#pragma unroll
  for (int i = 0; i < NACC; i++)
#pragma unroll
    for (int j = 0; j < 4; j++)
#pragma unroll
      for (int r = 0; r < 4; r++) {
        int row = r0g + i * 16 + r;
        int col = c0g + j * 16;
        float v = acc[i][j][r];
        if (MODE == 1)      ((float*)Cout)[(size_t)row * N + col] = v;
        else if (MODE == 0) ((u16*)Cout)[(size_t)row * N + col]  = f2b(v);
        else {
          if (col < 1024) ((u16*)Cout)[(size_t)row * 1024 + col] = f2b(v);
          else            ((u16*)Cout2)[(size_t)(col - 1024) * M + row] = f2b(v);
        }
      }
}

// ---------------- launch ----------------
extern "C" void kernel_launch(void* const* d_in, const int* in_sizes, int n_in,
                              void* d_out, int out_size, void* d_ws, size_t ws_size,
                              hipStream_t stream) {
  const float* x  = (const float*)d_in[0];
  const float* wq = (const float*)d_in[1];
  const float* wk = (const float*)d_in[2];
  const float* wv = (const float*)d_in[3];
  const float* wo = (const float*)d_in[4];
  const float* fc = (const float*)d_in[5];
  const float* fs = (const float*)d_in[6];

  char* ws = (char*)d_ws;
  u16* Xb  = (u16*)(ws);                 // 33.5 MB  (later reused as Ow)
  u16* Wqb = (u16*)(ws + 33554432);      // 33.5 MB  (later reused as Wob)
  u16* Wkv = (u16*)(ws + 67108864);      // 16.8 MB  (K rows 0..1023, V rows 1024..2047)
  u16* Qw  = (u16*)(ws + 83886080);      // 33.5 MB
  u16* Kw  = (u16*)(ws + 117440512);     // 8.4 MB
  u16* Vw  = (u16*)(ws + 125829120);     // 8.4 MB  (V^T layout [1024][4096])
  u16* Ow  = Xb;
  u16* Wob = Wqb;

  auto cvt = [&](const float* in, u16* out, int n) {
    int n4 = n >> 2;
    int blocks = (n4 + 255) / 256; if (blocks > 2048) blocks = 2048;
    cvt_kernel<<<dim3(blocks), dim3(256), 0, stream>>>(in, out, n4);
  };
  cvt(x,  Xb,  B_ * S_ * DIM_);
  cvt(wq, Wqb, DIM_ * DIM_);
  cvt(wk, Wkv, NKV_ * HD_ * DIM_);
  cvt(wv, Wkv + (size_t)1024 * 4096, NKV_ * HD_ * DIM_);

  // Q-proj: 256x256 tiles, grid 256 (exact round)
  gemm256<0, false><<<dim3(16 * 16), 512, 0, stream>>>(Xb, Wqb, Qw, nullptr, 4096, 4096, 4096);
  // KV-proj: 128x256 tiles, grid 32*8 = 256 (exact round)
  gemm256<3, true><<<dim3(32 * 8), 512, 0, stream>>>(Xb, Wkv, Kw, Vw, 4096, 2048, 4096);

  cvt(wo, Wob, DIM_ * DIM_);

  rope_kernel<<<dim3((B_ * S_ * NKV_ * 64) / 256), 256, 0, stream>>>(Kw, fc, fs, NKV_);

  // attn: 128 q-rows/block, 8 waves, grid 1024 = 4 blocks/CU
  attn_kernel<<<dim3(B_ * NH_ * (S_ / 128)), 512, 0, stream>>>(Qw, Kw, Vw, Ow, fc, fs);

  // O-proj: 256x256 tiles, grid 256 (exact round)
  gemm256<1, false><<<dim3(16 * 16), 512, 0, stream>>>(Ow, Wob, d_out, nullptr, 4096, 4096, 4096);
}

// Round 21
// 504.630 us; speedup vs baseline: 1.0063x; 1.0018x over previous
//
#include <hip/hip_runtime.h>

typedef unsigned short u16;
typedef unsigned int u32;
typedef __bf16 bf16_t;
typedef bf16_t bf16x8 __attribute__((ext_vector_type(8)));
typedef float f32x4 __attribute__((ext_vector_type(4)));

#define B_ 2
#define S_ 2048
#define DIM_ 4096
#define NH_ 32
#define NKV_ 8
#define HD_ 128

__device__ __forceinline__ u16 f2b(float f) {
  union { float f; unsigned u; } x; x.f = f;
  unsigned r = x.u + 0x7fffu + ((x.u >> 16) & 1u);
  return (u16)(r >> 16);
}
__device__ __forceinline__ float b2f(u16 u) {
  union { unsigned u; float f; } x; x.u = ((unsigned)u) << 16;
  return x.f;
}
__device__ __forceinline__ u32 cvtpk(float lo, float hi) {
  u32 r;
  asm volatile("v_cvt_pk_bf16_f32 %0, %1, %2" : "=v"(r) : "v"(lo), "v"(hi));
  return r;
}
// cross-lane reduce over lanes {l, l^16, l^32, l^48} — proven shfl_xor path
__device__ __forceinline__ float redmax4(float x) {
  x = fmaxf(x, __shfl_xor(x, 16));
  x = fmaxf(x, __shfl_xor(x, 32));
  return x;
}
__device__ __forceinline__ float redsum4(float x) {
  x += __shfl_xor(x, 16);
  x += __shfl_xor(x, 32);
  return x;
}

#define GLDS(gsrc, ldst) \
  __builtin_amdgcn_global_load_lds((const __attribute__((address_space(1))) void*)(gsrc), \
                                   (__attribute__((address_space(3))) void*)(ldst), 16, 0, 0)
#define BAR()    __builtin_amdgcn_s_barrier()
#define SCHED0() __builtin_amdgcn_sched_barrier(0)

// ---------------- f32 -> bf16 conversion ----------------
__global__ void cvt_kernel(const float* __restrict__ in, u16* __restrict__ out, int n4) {
  int i = blockIdx.x * blockDim.x + threadIdx.x;
  int stride = gridDim.x * blockDim.x;
  for (; i < n4; i += stride) {
    float4 v = ((const float4*)in)[i];
    ushort4 o;
    o.x = f2b(v.x); o.y = f2b(v.y); o.z = f2b(v.z); o.w = f2b(v.w);
    ((ushort4*)out)[i] = o;
  }
}

// ---------------- RoPE (in-place on bf16) — K only ----------------
__global__ void rope_kernel(u16* __restrict__ t, const float* __restrict__ fc,
                            const float* __restrict__ fs, int nheads) {
  int idx = blockIdx.x * blockDim.x + threadIdx.x;
  int ppr = nheads * 64;
  int row = idx / ppr;
  int pr = idx - row * ppr;
  int h = pr >> 6, j = pr & 63;
  int s = row & (S_ - 1);
  float c = fc[s * 64 + j], sn = fs[s * 64 + j];
  u16* p = t + (size_t)row * (size_t)(nheads * HD_) + h * HD_ + j * 2;
  float tr = b2f(p[0]), ti = b2f(p[1]);
  p[0] = f2b(tr * c - ti * sn);
  p[1] = f2b(tr * sn + ti * c);
}

// ---------------- Flash attention (causal, GQA 4:1), KVBLK = 64 ----------------
// Block = 128 q rows of one (b,h); 8 waves x 16 q; KV tile = 64 keys, dbuf;
// grid 1024. 64-key tiles halve per-key fixed costs (barriers, vmcnt drains,
// shuffle reduces, defer-checks) vs the 32-key version.
// K in LDS: [64][128] rows (256B), XOR ((key&7)<<4), pre-swizzled global source.
// V^T in LDS: [128][64] rows (128B), XOR ((d&7)<<4); write side (lane>>3)&7 == d&7
// so the source permutation and read permutation are the same involution.
__global__ __launch_bounds__(512) void attn_kernel(const u16* __restrict__ Q,
                                                   const u16* __restrict__ Kt,
                                                   const u16* __restrict__ VT,
                                                   u16* __restrict__ O,
                                                   const float* __restrict__ fc,
                                                   const float* __restrict__ fs) {
  __shared__ u16 Ks[2][64 * 128];
  __shared__ u16 Vs[2][128 * 64];

  const int bid = blockIdx.x;
  const int qb = 15 - (bid >> 6);        // heavy blocks first (128-row q blocks)
  const int h = bid & 31;
  const int b = (bid >> 5) & 1;
  const int g = h >> 2;
  const int tid = threadIdx.x;
  const int lane = tid & 63;
  const int wv = tid >> 6;               // 0..7
  const int qrow0 = qb * 128 + wv * 16;
  const float scl2 = 0.12751744f;        // (1/sqrt(128)) * log2(e)

  const int qloc = lane & 15;
  const int grp = lane >> 4;

  // ---- Q fragment with fused RoPE ----
  bf16x8 qf[4];
  {
    const int qr = qrow0 + qloc;
    const u16* qptr = Q + (size_t)(b * S_ + qr) * (NH_ * HD_) + h * HD_ + grp * 8;
#pragma unroll
    for (int c = 0; c < 4; c++) {
      union { bf16x8 v; u16 u[8]; } raw;
      raw.v = *(const bf16x8*)(qptr + c * 32);
      const int p0 = c * 16 + grp * 4;
      const float4 cv = *(const float4*)&fc[(size_t)qr * 64 + p0];
      const float4 sv = *(const float4*)&fs[(size_t)qr * 64 + p0];
      union { bf16x8 v; u32 w[4]; } out;
      const float cc[4] = {cv.x, cv.y, cv.z, cv.w};
      const float ss[4] = {sv.x, sv.y, sv.z, sv.w};
#pragma unroll
      for (int j = 0; j < 4; j++) {
        float tr = b2f(raw.u[2 * j]), ti = b2f(raw.u[2 * j + 1]);
        out.w[j] = cvtpk(tr * cc[j] - ti * ss[j], tr * ss[j] + ti * cc[j]);
      }
      qf[c] = out.v;
    }
  }

  float m = -1e30f, l = 0.f;
  f32x4 o[8];
#pragma unroll
  for (int c = 0; c < 8; c++)
#pragma unroll
    for (int r = 0; r < 4; r++) o[c][r] = 0.f;

  const int nkv = 2 * qb + 2;            // 64-key tiles; always even

  // ---- loop-invariant LDS read byte-offsets ----
  // K: addr(n,c) = ka[c] + n*4096  (krow = n*16+qloc; (n*16)&7 == 0)
  int ka[4];
#pragma unroll
  for (int c = 0; c < 4; c++)
    ka[c] = qloc * 256 + ((c * 64 + grp * 16) ^ ((qloc & 7) << 4));
  // V^T: addr(s,c) = va[s][c]  (d = c*16+qloc; s = key slab 0/1)
  int va[2][8];
#pragma unroll
  for (int s = 0; s < 2; s++)
#pragma unroll
    for (int c = 0; c < 8; c++) {
      int d = c * 16 + qloc;
      va[s][c] = d * 128 + (((s * 64) | (grp * 16)) ^ ((d & 7) << 4));
    }

  // ---- staging geometry ----
  // K: lane -> row wv*4 + grp (+p*32), col (lane&15)*16B, pre-swizzled source
  const int kkey = wv * 4 + grp;
  const int cbsK = (qloc * 16) ^ ((kkey & 7) << 4);
  // V^T: lane -> d wv*8 + (lane>>3) (+p*64), col (lane&7)*16B, pre-swizzled
  const int vd = wv * 8 + (lane >> 3);
  const int cbsV = ((lane & 7) * 16) ^ (((lane >> 3) & 7) << 4);

  const u16* kp = Kt + (size_t)(b * S_ + kkey) * 1024 + g * HD_ + (cbsK >> 1);
  const u16* vp = VT + (size_t)(g * HD_ + vd) * 4096 + (size_t)b * S_ + (cbsV >> 1);

#define STAGE_KV(T, buf) { \
    GLDS(kp,              &Ks[buf][wv * 512]); \
    GLDS(kp + 32 * 1024,  &Ks[buf][(8 + wv) * 512]); \
    GLDS(vp,              &Vs[buf][wv * 512]); \
    GLDS(vp + 64 * 4096,  &Vs[buf][(8 + wv) * 512]); \
    kp += 64 * 1024; \
    vp += 64; }

  // prologue: stage tile 0 into buf 0
  STAGE_KV(0, 0)

#define ATTN_ITER(T, CB, NB)                                                   \
  {                                                                            \
    const bool pf = ((T) + 1 < nkv);                                           \
    if (pf) {                                                                  \
      STAGE_KV((T) + 1, NB)                                                    \
      asm volatile("s_waitcnt vmcnt(4)" ::: "memory");                         \
    } else {                                                                   \
      asm volatile("s_waitcnt vmcnt(0)" ::: "memory");                         \
    }                                                                          \
    BAR();                                                                     \
    SCHED0();                                                                  \
    if ((T) * 64 <= qrow0 + 15) {                                              \
      f32x4 s[4];                                                              \
      __builtin_amdgcn_s_setprio(1);                                           \
      _Pragma("unroll")                                                        \
      for (int n = 0; n < 4; n++) {                                            \
        f32x4 sc;                                                              \
        _Pragma("unroll")                                                      \
        for (int r = 0; r < 4; r++) sc[r] = 0.f;                               \
        _Pragma("unroll")                                                      \
        for (int c = 0; c < 4; c++) {                                          \
          bf16x8 kf = *(const bf16x8*)((const char*)Ks[CB] + ka[c] + n * 4096);\
          sc = __builtin_amdgcn_mfma_f32_16x16x32_bf16(kf, qf[c], sc, 0, 0, 0);\
        }                                                                      \
        s[n] = sc;                                                             \
      }                                                                        \
      __builtin_amdgcn_s_setprio(0);                                           \
      const int q = qrow0 + qloc;                                              \
      if ((T) * 64 + 63 > qrow0) {                                             \
        _Pragma("unroll")                                                      \
        for (int n = 0; n < 4; n++)                                            \
          _Pragma("unroll")                                                    \
          for (int r = 0; r < 4; r++) {                                        \
            int k = (T) * 64 + n * 16 + grp * 4 + r;                           \
            if (k > q) s[n][r] = -1e9f;                                        \
          }                                                                    \
      }                                                                        \
      float pmax = fmaxf(fmaxf(fmaxf(s[0][0], s[0][1]), fmaxf(s[0][2], s[0][3])), \
                         fmaxf(fmaxf(s[1][0], s[1][1]), fmaxf(s[1][2], s[1][3]))); \
      pmax = fmaxf(pmax,                                                       \
             fmaxf(fmaxf(fmaxf(s[2][0], s[2][1]), fmaxf(s[2][2], s[2][3])),    \
                   fmaxf(fmaxf(s[3][0], s[3][1]), fmaxf(s[3][2], s[3][3]))));  \
      pmax = redmax4(pmax);                                                    \
      if (__any(pmax > m + 64.f)) {                                            \
        float mn = fmaxf(m, pmax);                                             \
        float alpha = exp2f((m - mn) * scl2);                                  \
        m = mn;                                                                \
        l *= alpha;                                                            \
        float ar[4];                                                           \
        _Pragma("unroll")                                                      \
        for (int r = 0; r < 4; r++) ar[r] = __shfl(alpha, grp * 4 + r);        \
        _Pragma("unroll")                                                      \
        for (int c = 0; c < 8; c++)                                            \
          _Pragma("unroll")                                                    \
          for (int r = 0; r < 4; r++) o[c][r] *= ar[r];                        \
      }                                                                        \
      const float msc = m * scl2;                                              \
      float p[4][4];                                                           \
      _Pragma("unroll")                                                        \
      for (int n = 0; n < 4; n++)                                              \
        _Pragma("unroll")                                                      \
        for (int r = 0; r < 4; r++)                                            \
          p[n][r] = exp2f(fmaf(s[n][r], scl2, -msc));                          \
      float rs = (((p[0][0] + p[0][1]) + (p[0][2] + p[0][3])) +                \
                  ((p[1][0] + p[1][1]) + (p[1][2] + p[1][3]))) +               \
                 (((p[2][0] + p[2][1]) + (p[2][2] + p[2][3])) +                \
                  ((p[3][0] + p[3][1]) + (p[3][2] + p[3][3])));                \
      l += redsum4(rs);                                                        \
      bf16x8 pa[2];                                                            \
      _Pragma("unroll")                                                        \
      for (int sl = 0; sl < 2; sl++) {                                         \
        u32 a0 = cvtpk(p[2 * sl][0], p[2 * sl][1]);                            \
        u32 a1 = cvtpk(p[2 * sl][2], p[2 * sl][3]);                            \
        u32 b0 = cvtpk(p[2 * sl + 1][0], p[2 * sl + 1][1]);                    \
        u32 b1 = cvtpk(p[2 * sl + 1][2], p[2 * sl + 1][3]);                    \
        asm volatile("v_permlane32_swap_b32 %0, %1" : "+v"(a0), "+v"(b0));     \
        asm volatile("v_permlane32_swap_b32 %0, %1" : "+v"(a1), "+v"(b1));     \
        asm volatile("v_permlane16_swap_b32 %0, %1" : "+v"(a0), "+v"(b0));     \
        asm volatile("v_permlane16_swap_b32 %0, %1" : "+v"(a1), "+v"(b1));     \
        union { bf16x8 v; u32 w[4]; } pau;                                     \
        pau.w[0] = a0; pau.w[1] = a1; pau.w[2] = b0; pau.w[3] = b1;            \
        pa[sl] = pau.v;                                                        \
      }                                                                        \
      __builtin_amdgcn_s_setprio(1);                                           \
      _Pragma("unroll")                                                        \
      for (int c = 0; c < 8; c++) {                                            \
        bf16x8 vf0 = *(const bf16x8*)((const char*)Vs[CB] + va[0][c]);         \
        bf16x8 vf1 = *(const bf16x8*)((const char*)Vs[CB] + va[1][c]);         \
        o[c] = __builtin_amdgcn_mfma_f32_16x16x32_bf16(pa[0], vf0, o[c], 0, 0, 0); \
        o[c] = __builtin_amdgcn_mfma_f32_16x16x32_bf16(pa[1], vf1, o[c], 0, 0, 0); \
      }                                                                        \
      __builtin_amdgcn_s_setprio(0);                                           \
    }                                                                          \
    asm volatile("s_waitcnt lgkmcnt(0)" ::: "memory");                         \
    SCHED0();                                                                  \
    BAR();                                                                     \
  }

  for (int t = 0; t < nkv; t += 2) {
    ATTN_ITER(t, 0, 1);
    ATTN_ITER(t + 1, 1, 0);
  }
#undef ATTN_ITER
#undef STAGE_KV

  // ---- epilogue ----
  float lr[4];
#pragma unroll
  for (int r = 0; r < 4; r++) lr[r] = 1.0f / __shfl(l, grp * 4 + r);
#pragma unroll
  for (int c = 0; c < 8; c++)
#pragma unroll
    for (int r = 0; r < 4; r++) {
      int qo = qrow0 + grp * 4 + r;
      float val = o[c][r] * lr[r];
      O[(size_t)(b * S_ + qo) * (NH_ * HD_) + h * HD_ + c * 16 + qloc] = f2b(val);
    }
}

// ---------------- 8-phase GEMM: C = A[M,K] * B[N,K]^T ----------------
// Tile = (SM ? 128 : 256) x 256, BK=64, 8 waves (2M x 4N), dbuf LDS, counted vmcnt.
// Barrier-reduced schedule (10 barriers/iter): per phase
//   [frag ds_reads; BAR; lgkmcnt(0); MFMA burst; stage (post-MFMA)]
// with the post-MFMA barrier kept ONLY at ph3/ph7 (after vmcnt(4)).
// MODE 0: bf16 row-major ld N; MODE 1: f32 row-major ld N;
// MODE 3: dual (col<1024 -> Cout bf16 ld 1024; col>=1024 -> Cout2 bf16 col-major [col-1024][M])
template<int MODE, bool SM>
__global__ __launch_bounds__(512, 2) void gemm256(const u16* __restrict__ A,
                                                  const u16* __restrict__ B,
                                                  void* __restrict__ Cout,
                                                  void* __restrict__ Cout2,
                                                  int M, int N, int K) {
  constexpr int BM = SM ? 128 : 256;
  constexpr int AH = SM ? 4096 : 8192;   // u16 per A-half
  constexpr int II = SM ? 1 : 2;         // m-frags per quadrant
  constexpr int NACC = SM ? 4 : 8;
  __shared__ u16 As[2][2][AH];
  __shared__ u16 Bs[2][2][8192];
  const int nbn = N >> 8;
  const int nwg = gridDim.x;
  int wg = blockIdx.x;
  wg = (wg & 7) * (nwg >> 3) + (wg >> 3);   // XCD swizzle (nwg % 8 == 0)
  const int bm = wg / nbn;
  const int bn = wg - bm * nbn;
  const int tid = threadIdx.x;
  const int lane = tid & 63;
  const int wv = tid >> 6;
  const int wm = wv >> 2, wn = wv & 3;
  const int qloc = lane & 15, grp = lane >> 4;
  const int NT = K >> 6;

  f32x4 acc[NACC][4];
#pragma unroll
  for (int i = 0; i < NACC; i++)
#pragma unroll
    for (int j = 0; j < 4; j++)
#pragma unroll
      for (int r = 0; r < 4; r++) acc[i][j][r] = 0.0f;

  const int srowl = lane >> 3;
  const int scsw = 8 * ((lane & 7) ^ srowl);   // pre-swizzled source col (elems)
  const size_t rowA = SM ? ((size_t)(bm * 128 + wv * 8 + srowl) * K + scsw)
                         : ((size_t)(bm * 256 + wv * 16 + srowl) * K + scsw);
  const size_t rowB = (size_t)(bn * 256 + wv * 16 + srowl) * K + scsw;

#define STAGE_A(buf, h, tt) { \
    if (SM) { \
      GLDS(A + rowA + (size_t)((h) * 64) * K + (size_t)(tt) * 64, &As[buf][h][wv * 512]); \
    } else { \
      GLDS(A + rowA + (size_t)((h) * 128) * K + (size_t)(tt) * 64, &As[buf][h][wv * 1024]); \
      GLDS(A + rowA + (size_t)((h) * 128 + 8) * K + (size_t)(tt) * 64, &As[buf][h][wv * 1024 + 512]); } }
#define STAGE_B(buf, h, tt) { \
    GLDS(B + rowB + (size_t)((h) * 128) * K + (size_t)(tt) * 64, &Bs[buf][h][wv * 1024]); \
    GLDS(B + rowB + (size_t)((h) * 128 + 8) * K + (size_t)(tt) * 64, &Bs[buf][h][wv * 1024 + 512]); }

  // ---- prologue: tile0 (A+B) into buf0, tile1 B into buf1 ----
  STAGE_A(0, 0, 0); STAGE_A(0, 1, 0);
  STAGE_B(0, 0, 0); STAGE_B(0, 1, 0);
  STAGE_B(1, 0, 1); STAGE_B(1, 1, 1);
  asm volatile("s_waitcnt vmcnt(4)" ::: "memory");   // tile0 fully landed
  BAR();

  for (int t = 0; t < NT; t += 2) {
#pragma unroll
    for (int half = 0; half < 2; half++) {
      bf16x8 bfr[4][2];
#pragma unroll
      for (int qd = 0; qd < 4; qd++) {
        if (qd == 0) {
#pragma unroll
          for (int j = 0; j < 4; j++)
#pragma unroll
            for (int ks = 0; ks < 2; ks++) {
              int rb = (wn & 1) * 64 + j * 16 + qloc;
              bfr[j][ks] = *(const bf16x8*)((const char*)&Bs[half][wn >> 1][0]
                           + rb * 128 + ((ks * 64 + grp * 16) ^ ((rb & 7) << 4)));
            }
        }
        bf16x8 af[II][2];
#pragma unroll
        for (int ii = 0; ii < II; ii++)
#pragma unroll
          for (int ks = 0; ks < 2; ks++) {
            int rh = SM ? (qd * 16 + qloc) : (qd * 32 + ii * 16 + qloc);
            af[ii][ks] = *(const bf16x8*)((const char*)&As[half][wm][0]
                         + rh * 128 + ((ks * 64 + grp * 16) ^ ((rh & 7) << 4)));
          }
        BAR();
        asm volatile("s_waitcnt lgkmcnt(0)" ::: "memory");
        SCHED0();
        __builtin_amdgcn_s_setprio(1);
#pragma unroll
        for (int ii = 0; ii < II; ii++)
#pragma unroll
          for (int ks = 0; ks < 2; ks++)
#pragma unroll
            for (int j = 0; j < 4; j++)
              acc[qd * II + ii][j] = __builtin_amdgcn_mfma_f32_16x16x32_bf16(
                  af[ii][ks], bfr[j][ks], acc[qd * II + ii][j], 0, 0, 0);
        __builtin_amdgcn_s_setprio(0);
        SCHED0();
        // ---- stage (post-MFMA; overlaps following phases' reads) ----
        const int ph = half * 4 + qd;
        if (ph == 0)      { STAGE_A(1, 0, t + 1); STAGE_A(1, 1, t + 1); }
        else if (ph == 1) { if (t + 2 < NT) { STAGE_B(0, 0, t + 2); STAGE_B(0, 1, t + 2); } }
        else if (ph == 4) { if (t + 2 < NT) { STAGE_A(0, 0, t + 2); STAGE_A(0, 1, t + 2); } }
        else if (ph == 5) { if (t + 3 < NT) { STAGE_B(1, 0, t + 3); STAGE_B(1, 1, t + 3); } }
        if (qd == 3) {
          if ((half == 0 ? t + 2 : t + 3) < NT)
            asm volatile("s_waitcnt vmcnt(4)" ::: "memory");
          else
            asm volatile("s_waitcnt vmcnt(0)" ::: "memory");
          BAR();
        }
      }
    }
  }
#undef STAGE_A
#undef STAGE_B

  // ---- epilogue ----
  const int r0g = bm * BM + wm * (BM / 2) + grp * 4;
  const int c0g = bn * 256 + wn * 64 + qloc;
#pragma unroll
  for (int i = 0; i < NACC; i++)
#pragma unroll
    for (int j = 0; j < 4; j++)
#pragma unroll
      for (int r = 0; r < 4; r++) {
        int row = r0g + i * 16 + r;
        int col = c0g + j * 16;
        float v = acc[i][j][r];
        if (MODE == 1)      ((float*)Cout)[(size_t)row * N + col] = v;
        else if (MODE == 0) ((u16*)Cout)[(size_t)row * N + col]  = f2b(v);
        else {
          if (col < 1024) ((u16*)Cout)[(size_t)row * 1024 + col] = f2b(v);
          else            ((u16*)Cout2)[(size_t)(col - 1024) * M + row] = f2b(v);
        }
      }
}

// ---------------- launch ----------------
extern "C" void kernel_launch(void* const* d_in, const int* in_sizes, int n_in,
                              void* d_out, int out_size, void* d_ws, size_t ws_size,
                              hipStream_t stream) {
  const float* x  = (const float*)d_in[0];
  const float* wq = (const float*)d_in[1];
  const float* wk = (const float*)d_in[2];
  const float* wv = (const float*)d_in[3];
  const float* wo = (const float*)d_in[4];
  const float* fc = (const float*)d_in[5];
  const float* fs = (const float*)d_in[6];

  char* ws = (char*)d_ws;
  u16* Xb  = (u16*)(ws);                 // 33.5 MB  (later reused as Ow)
  u16* Wqb = (u16*)(ws + 33554432);      // 33.5 MB  (later reused as Wob)
  u16* Wkv = (u16*)(ws + 67108864);      // 16.8 MB  (K rows 0..1023, V rows 1024..2047)
  u16* Qw  = (u16*)(ws + 83886080);      // 33.5 MB
  u16* Kw  = (u16*)(ws + 117440512);     // 8.4 MB
  u16* Vw  = (u16*)(ws + 125829120);     // 8.4 MB  (V^T layout [1024][4096])
  u16* Ow  = Xb;
  u16* Wob = Wqb;

  auto cvt = [&](const float* in, u16* out, int n) {
    int n4 = n >> 2;
    int blocks = (n4 + 255) / 256; if (blocks > 2048) blocks = 2048;
    cvt_kernel<<<dim3(blocks), dim3(256), 0, stream>>>(in, out, n4);
  };
  cvt(x,  Xb,  B_ * S_ * DIM_);
  cvt(wq, Wqb, DIM_ * DIM_);
  cvt(wk, Wkv, NKV_ * HD_ * DIM_);
  cvt(wv, Wkv + (size_t)1024 * 4096, NKV_ * HD_ * DIM_);

  // Q-proj: 256x256 tiles, grid 256 (exact round)
  gemm256<0, false><<<dim3(16 * 16), 512, 0, stream>>>(Xb, Wqb, Qw, nullptr, 4096, 4096, 4096);
  // KV-proj: 128x256 tiles, grid 32*8 = 256 (exact round)
  gemm256<3, true><<<dim3(32 * 8), 512, 0, stream>>>(Xb, Wkv, Kw, Vw, 4096, 2048, 4096);

  cvt(wo, Wob, DIM_ * DIM_);

  rope_kernel<<<dim3((B_ * S_ * NKV_ * 64) / 256), 256, 0, stream>>>(Kw, fc, fs, NKV_);

  // attn: 128 q-rows/block, 8 waves, KVBLK=64, grid 1024
  attn_kernel<<<dim3(B_ * NH_ * (S_ / 128)), 512, 0, stream>>>(Qw, Kw, Vw, Ow, fc, fs);

  // O-proj: 256x256 tiles, grid 256 (exact round)
  gemm256<1, false><<<dim3(16 * 16), 512, 0, stream>>>(Ow, Wob, d_out, nullptr, 4096, 4096, 4096);
}